// Round 2
// baseline (169.045 us; speedup 1.0000x reference)
//
#include <hip/hip_runtime.h>

// LIF neuron scan: v = v*0.5 + x[t]; s = (v - 0.5 > 0); v -= s*0.5
// One thread per (batch, neuron) row; T=100 contiguous floats per row.
// Round 1 -> 2: bulk-load entire row into registers (25 float4, all loads
// in flight) -> compute in place -> bulk store. Attacks latency-boundedness
// (VGPR=32 meant ~no MLP) and write-merge inefficiency (WRITE_SIZE 1.31x).

#define T_STEPS   100
#define T_VEC     25      // 100 / 4
#define DECAY     0.5f
#define VTH       0.5f

__global__ __launch_bounds__(256) void lif_kernel(const float* __restrict__ x,
                                                  float* __restrict__ out,
                                                  int n_rows) {
    int row = blockIdx.x * blockDim.x + threadIdx.x;
    if (row >= n_rows) return;

    const float4* __restrict__ xr   = reinterpret_cast<const float4*>(x)   + (size_t)row * T_VEC;
    float4* __restrict__       orow = reinterpret_cast<float4*>(out)       + (size_t)row * T_VEC;

    // Phase 1: issue ALL loads before any use -> 25 outstanding 16B loads/lane.
    float4 buf[T_VEC];
    #pragma unroll
    for (int j = 0; j < T_VEC; ++j) {
        buf[j] = xr[j];
    }

    // Phase 2: sequential LIF recurrence, spikes overwrite inputs in place.
    float v = 0.0f;
    #pragma unroll
    for (int j = 0; j < T_VEC; ++j) {
        float xs[4] = {buf[j].x, buf[j].y, buf[j].z, buf[j].w};
        float ss[4];
        #pragma unroll
        for (int k = 0; k < 4; ++k) {
            // v*0.5 exact (pow2), s*0.5 in {0,0.5} exact -> bitwise == reference.
            v = v * DECAY + xs[k];
            float sk = (v - VTH > 0.0f) ? 1.0f : 0.0f;
            v -= sk * VTH;
            ss[k] = sk;
        }
        buf[j].x = ss[0]; buf[j].y = ss[1]; buf[j].z = ss[2]; buf[j].w = ss[3];
    }

    // Phase 3: bulk store, 4 consecutive 16B stores per 64B line -> full-line
    // merge in L2.
    #pragma unroll
    for (int j = 0; j < T_VEC; ++j) {
        orow[j] = buf[j];
    }
}

extern "C" void kernel_launch(void* const* d_in, const int* in_sizes, int n_in,
                              void* d_out, int out_size, void* d_ws, size_t ws_size,
                              hipStream_t stream) {
    const float* x = (const float*)d_in[0];
    float* out = (float*)d_out;

    int n_rows = in_sizes[0] / T_STEPS;   // 32 * 16384 = 524288
    int block = 256;
    int grid = (n_rows + block - 1) / block;  // 2048

    lif_kernel<<<grid, block, 0, stream>>>(x, out, n_rows);
}

// Round 3
// 138.119 us; speedup vs baseline: 1.2239x; 1.2239x over previous
//
#include <hip/hip_runtime.h>

// LIF neuron scan: v = v*0.5 + x[t]; s = (v - 0.5 > 0); v -= s*0.5
// Round 2 -> 3: rows are contiguous 400B segments and consecutive rows are
// adjacent, so 64 rows = one contiguous 25.6KB region. Stage via LDS:
//   coalesced float4 load -> LDS de-stride -> per-thread serial LIF in LDS
//   (stride 101, odd -> 2 lanes/bank = conflict-free) -> coalesced store.
// Kills the 1.5x partial-line write amplification (WRITE_SIZE 315MB -> 210MB)
// that capped round 2 at ~1.9 TB/s effective write throughput.

#define T_STEPS 100
#define T_VEC   25      // float4 per row
#define ROWS    64      // rows per block == blockDim.x == one wave
#define STRIDE  101     // LDS row stride in dwords; odd -> conflict-free walks
#define DECAY   0.5f
#define VTH     0.5f

__global__ __launch_bounds__(64) void lif_kernel(const float* __restrict__ x,
                                                 float* __restrict__ out,
                                                 int n_rows) {
    __shared__ float tile[ROWS * STRIDE];   // 25,856 B -> 6 blocks/CU

    const int tid = threadIdx.x;
    const long long row0 = (long long)blockIdx.x * ROWS;
    const long long total_f4 = (long long)n_rows * T_VEC;

    const float4* __restrict__ xr = reinterpret_cast<const float4*>(x) + row0 * T_VEC;
    float4* __restrict__ orow     = reinterpret_cast<float4*>(out)     + row0 * T_VEC;

    // Phase 1: coalesced load of 64 contiguous rows (25.6 KB, 1 KB per wave
    // instruction) into LDS, de-strided to tile[row][col].
    #pragma unroll
    for (int k = 0; k < T_VEC; ++k) {
        int f = k * ROWS + tid;                 // float4 index in block region
        if (row0 * T_VEC + f < total_f4) {
            float4 w = xr[f];
            int row = f / T_VEC;                // const-div -> magic mul
            int c4  = f % T_VEC;
            int base = row * STRIDE + c4 * 4;
            tile[base + 0] = w.x;
            tile[base + 1] = w.y;
            tile[base + 2] = w.z;
            tile[base + 3] = w.w;
        }
    }
    __syncthreads();

    // Phase 2: serial LIF per row, spike overwrites input in place.
    if (row0 + tid < n_rows) {
        float v = 0.0f;
        const int rbase = tid * STRIDE;
        #pragma unroll 10
        for (int t = 0; t < T_STEPS; ++t) {
            float xv = tile[rbase + t];
            // v*0.5 exact (pow2); s*0.5 in {0,0.5} exact -> bitwise == ref.
            v = v * DECAY + xv;
            float s = (v - VTH > 0.0f) ? 1.0f : 0.0f;
            v -= s * VTH;
            tile[rbase + t] = s;
        }
    }
    __syncthreads();

    // Phase 3: coalesced full-line store of the spike tile.
    #pragma unroll
    for (int k = 0; k < T_VEC; ++k) {
        int f = k * ROWS + tid;
        if (row0 * T_VEC + f < total_f4) {
            int row = f / T_VEC;
            int c4  = f % T_VEC;
            int base = row * STRIDE + c4 * 4;
            float4 w;
            w.x = tile[base + 0];
            w.y = tile[base + 1];
            w.z = tile[base + 2];
            w.w = tile[base + 3];
            orow[f] = w;
        }
    }
}

extern "C" void kernel_launch(void* const* d_in, const int* in_sizes, int n_in,
                              void* d_out, int out_size, void* d_ws, size_t ws_size,
                              hipStream_t stream) {
    const float* x = (const float*)d_in[0];
    float* out = (float*)d_out;

    int n_rows = in_sizes[0] / T_STEPS;           // 32 * 16384 = 524288
    int grid = (n_rows + ROWS - 1) / ROWS;        // 8192

    lif_kernel<<<grid, ROWS, 0, stream>>>(x, out, n_rows);
}

// Round 4
// 97.564 us; speedup vs baseline: 1.7327x; 1.4157x over previous
//
#include <hip/hip_runtime.h>

// LIF neuron scan: v = v*0.5 + x[t]; s = (v - 0.5 > 0); v -= s*0.5
// Round 3 -> 4: LDS off the critical path. Compute fully in registers
// (direct float4 global loads; L3 serves re-reads), spikes packed into 25
// float4 regs. LDS is only a store-bounce: b128 writes/reads with XOR
// swizzle (conflict-free by construction), split into two 32-row stages so
// LDS = 13.3 KB -> 12 blocks/CU (vs 6), __launch_bounds__(64,3).
// Keeps round-3's exact WRITE_SIZE (full-line coalesced stores).

#define T_STEPS 100
#define T_VEC   25      // float4 per row
#define ROWS    64      // rows per block (== blockDim.x, one wave)
#define HROWS   32      // rows per bounce stage
#define SLOTS   26      // float4 slots per row in LDS (25 + 1 pad for swizzle)
#define DECAY   0.5f
#define VTH     0.5f

__device__ __forceinline__ int swz(int c4, int row) {
    // XOR low 3 bits for c4 in [0,24); keep c4==24 unswizzled (stays in range).
    return (c4 < 24) ? (c4 ^ (row & 7)) : c4;
}

__global__ __launch_bounds__(64, 3) void lif_kernel(const float* __restrict__ x,
                                                    float* __restrict__ out,
                                                    int n_rows) {
    __shared__ float4 tile[HROWS * SLOTS];   // 13,312 B

    const int tid = threadIdx.x;
    const long long row0 = (long long)blockIdx.x * ROWS;
    const long long my_row = row0 + tid;

    // ---- Phase 1+2: load own row, compute LIF entirely in registers ----
    float4 buf[T_VEC];
    if (my_row < n_rows) {
        const float4* __restrict__ xr = reinterpret_cast<const float4*>(x) + my_row * T_VEC;
        float v = 0.0f;
        #pragma unroll
        for (int j = 0; j < T_VEC; ++j) {
            float4 xv = xr[j];
            float xs[4] = {xv.x, xv.y, xv.z, xv.w};
            float ss[4];
            #pragma unroll
            for (int k = 0; k < 4; ++k) {
                // v*0.5 exact (pow2); s*0.5 in {0,0.5} exact -> bitwise == ref.
                v = v * DECAY + xs[k];
                float sk = (v - VTH > 0.0f) ? 1.0f : 0.0f;
                v -= sk * VTH;
                ss[k] = sk;
            }
            buf[j].x = ss[0]; buf[j].y = ss[1]; buf[j].z = ss[2]; buf[j].w = ss[3];
        }
    }

    // ---- Phase 3: two-stage LDS bounce -> fully coalesced global stores ----
    const long long total_f4 = (long long)n_rows * T_VEC;
    float4* __restrict__ ob = reinterpret_cast<float4*>(out);

    #pragma unroll
    for (int stage = 0; stage < 2; ++stage) {
        const int rbase = stage * HROWS;           // first row of this stage
        // Stage write: the 32 owning lanes write their 25 float4, swizzled b128.
        if ((tid >> 5) == stage) {
            const int r = tid & (HROWS - 1);
            #pragma unroll
            for (int j = 0; j < T_VEC; ++j) {
                tile[r * SLOTS + swz(j, r)] = buf[j];
            }
        }
        __syncthreads();

        // Coalesced store: 32 rows * 25 f4 = 800 f4, 13 wave-iters.
        const long long gbase = (row0 + rbase) * T_VEC;   // f4 index of stage start
        #pragma unroll
        for (int k = 0; k < 13; ++k) {
            int f = k * ROWS + tid;                // 0..831
            if (f < HROWS * T_VEC && gbase + f < total_f4) {
                int row = f / T_VEC;               // magic-mul
                int c4  = f % T_VEC;
                ob[gbase + f] = tile[row * SLOTS + swz(c4, row)];
            }
        }
        __syncthreads();
    }
}

extern "C" void kernel_launch(void* const* d_in, const int* in_sizes, int n_in,
                              void* d_out, int out_size, void* d_ws, size_t ws_size,
                              hipStream_t stream) {
    const float* x = (const float*)d_in[0];
    float* out = (float*)d_out;

    int n_rows = in_sizes[0] / T_STEPS;           // 32 * 16384 = 524288
    int grid = (n_rows + ROWS - 1) / ROWS;        // 8192

    lif_kernel<<<grid, ROWS, 0, stream>>>(x, out, n_rows);
}

// Round 5
// 97.561 us; speedup vs baseline: 1.7327x; 1.0000x over previous
//
#include <hip/hip_runtime.h>

// LIF neuron scan: v = v*0.5 + x[t]; s = (v - 0.5 > 0); v -= s*0.5
// Round 4 -> 5: input path now mirrors the output path. R4's per-lane
// 400B-stride float4 reads moved 4KB per 1KB used per wave instruction
// (64 partial 64B lines); L1 can't hold lines across the 4 consuming
// iterations at 12 waves/CU. Now: coalesced full-line wave loads -> LDS
// (b128 + XOR swizzle) -> per-lane ds_read_b128 row grab into registers ->
// compute fully in regs -> two-stage LDS bounce-out (unchanged from R4).
// One 13.3KB tile reused for in and out; 12 blocks/CU (VGPR-capped anyway).

#define T_STEPS 100
#define T_VEC   25      // float4 per row
#define ROWS    64      // rows per block == blockDim.x (one wave)
#define HROWS   32      // rows per bounce stage
#define SLOTS   26      // float4 slots per LDS row (25 + 1 pad)
#define DECAY   0.5f
#define VTH     0.5f

__device__ __forceinline__ int swz(int c4, int row) {
    // XOR low 3 bits for c4 in [0,24); c4==24 stays (in range).
    // Per fixed c4, (2r + (c4^(r&7))) mod 8 is bijective over each 8-row
    // group -> minimal bank aliasing for b128 ops.
    return (c4 < 24) ? (c4 ^ (row & 7)) : c4;
}

__global__ __launch_bounds__(64, 3) void lif_kernel(const float* __restrict__ x,
                                                    float* __restrict__ out,
                                                    int n_rows) {
    __shared__ float4 tile[HROWS * SLOTS];   // 13,312 B -> 12 blocks/CU

    const int tid = threadIdx.x;
    const long long row0 = (long long)blockIdx.x * ROWS;
    const long long total_f4 = (long long)n_rows * T_VEC;
    const long long gf0 = row0 * T_VEC;

    const float4* __restrict__ xb = reinterpret_cast<const float4*>(x);
    float4* __restrict__ ob       = reinterpret_cast<float4*>(out);

    float4 buf[T_VEC];

    // ---- Input: two stages of {coalesced load -> LDS -> row grab} ----
    #pragma unroll
    for (int stage = 0; stage < 2; ++stage) {
        const long long gbase = gf0 + (long long)stage * (HROWS * T_VEC);
        #pragma unroll
        for (int k = 0; k < 13; ++k) {
            int f = k * ROWS + tid;            // 0..831
            if (f < HROWS * T_VEC && gbase + f < total_f4) {
                float4 w = xb[gbase + f];      // full-line coalesced stream
                int r  = f / T_VEC;            // magic-mul
                int c4 = f % T_VEC;
                tile[r * SLOTS + swz(c4, r)] = w;
            }
        }
        __syncthreads();
        if ((tid >> 5) == stage) {             // owning half-wave grabs rows
            const int r = tid & (HROWS - 1);
            #pragma unroll
            for (int j = 0; j < T_VEC; ++j)
                buf[j] = tile[r * SLOTS + swz(j, r)];
        }
        __syncthreads();                        // grabs done before reuse
    }

    // ---- Compute: 100-step LIF recurrence entirely in registers ----
    {
        float v = 0.0f;
        #pragma unroll
        for (int j = 0; j < T_VEC; ++j) {
            float xs[4] = {buf[j].x, buf[j].y, buf[j].z, buf[j].w};
            float ss[4];
            #pragma unroll
            for (int k = 0; k < 4; ++k) {
                // v*0.5 exact (pow2); s*0.5 in {0,0.5} exact -> bitwise == ref.
                v = v * DECAY + xs[k];
                float sk = (v - VTH > 0.0f) ? 1.0f : 0.0f;
                v -= sk * VTH;
                ss[k] = sk;
            }
            buf[j].x = ss[0]; buf[j].y = ss[1]; buf[j].z = ss[2]; buf[j].w = ss[3];
        }
    }

    // ---- Output: two stages of {row write -> coalesced store} ----
    #pragma unroll
    for (int stage = 0; stage < 2; ++stage) {
        if ((tid >> 5) == stage) {
            const int r = tid & (HROWS - 1);
            #pragma unroll
            for (int j = 0; j < T_VEC; ++j)
                tile[r * SLOTS + swz(j, r)] = buf[j];
        }
        __syncthreads();
        const long long gbase = gf0 + (long long)stage * (HROWS * T_VEC);
        #pragma unroll
        for (int k = 0; k < 13; ++k) {
            int f = k * ROWS + tid;
            if (f < HROWS * T_VEC && gbase + f < total_f4) {
                int r  = f / T_VEC;
                int c4 = f % T_VEC;
                ob[gbase + f] = tile[r * SLOTS + swz(c4, r)];
            }
        }
        __syncthreads();
    }
}

extern "C" void kernel_launch(void* const* d_in, const int* in_sizes, int n_in,
                              void* d_out, int out_size, void* d_ws, size_t ws_size,
                              hipStream_t stream) {
    const float* x = (const float*)d_in[0];
    float* out = (float*)d_out;

    int n_rows = in_sizes[0] / T_STEPS;           // 32 * 16384 = 524288
    int grid = (n_rows + ROWS - 1) / ROWS;        // 8192

    lif_kernel<<<grid, ROWS, 0, stream>>>(x, out, n_rows);
}